// Round 11
// baseline (309.318 us; speedup 1.0000x reference)
//
#include <hip/hip_runtime.h>
#include <hip/hip_bf16.h>
#include <stdint.h>

#define DIM 1024
#define NH 16
#define NKV 4
#define HD 64
#define SEQ 2048
#define BATCH 2
#define RANK 4
#define NSTEPS 2

// bf16 conversion-region element offsets (compile-time)
#define XN      4194304            // x: 4096*1024
#define WQ_END  5242880            // + 1024*1024
#define WK_END  5505024            // + 256*1024
#define WV_END  5767168            // + 256*1024
#define CVT_BLOCKS 6656
#define LORA_BLOCKS 1024

typedef unsigned short u16;
typedef unsigned int u32;
typedef __attribute__((ext_vector_type(8))) __bf16 bf16x8;
typedef __attribute__((ext_vector_type(4))) float f32x4;

__device__ __forceinline__ float bf2f(u16 v) {
    u32 u = ((u32)v) << 16;
    return __builtin_bit_cast(float, u);
}
__device__ __forceinline__ u16 f2bf(float f) {
    u32 u = __builtin_bit_cast(u32, f);
    u32 r = (u + 0x7fffu + ((u >> 16) & 1u)) >> 16;
    return (u16)r;
}
__device__ __forceinline__ u32 pk2(float a, float b) {
    return (u32)f2bf(a) | ((u32)f2bf(b) << 16);
}
// truncation-pack two fp32->bf16 in ONE v_perm_b32 (bias cancels in softmax)
__device__ __forceinline__ u32 pk2t(float a, float b) {
    return __builtin_amdgcn_perm(__builtin_bit_cast(u32, b),
                                 __builtin_bit_cast(u32, a), 0x07060302u);
}
// async global->LDS, 16 B per lane; lptr MUST be wave-uniform (HW adds lane*16)
__device__ __forceinline__ void glds16(const u16* g, u16* l) {
    __builtin_amdgcn_global_load_lds(
        (const __attribute__((address_space(1))) u32*)g,
        (__attribute__((address_space(3))) u32*)l, 16, 0, 0);
}

// ---------------- K_PREP: fused [fp32->bf16 convert | LoRA t = x@A^T] -------
__global__ __launch_bounds__(256) void k_prep(
    const float* __restrict__ x, const float* __restrict__ Wq,
    const float* __restrict__ Wk, const float* __restrict__ Wv,
    const float* __restrict__ Wp, u16* __restrict__ dst,
    const float* __restrict__ Aq, const float* __restrict__ Av,
    const int* __restrict__ step_p, float* __restrict__ tq, float* __restrict__ tv)
{
    int bx = blockIdx.x;
    if (bx < CVT_BLOCKS) {
        int e = (bx * 256 + threadIdx.x) * 4;
        const float* src;
        if (e < XN)          src = x  + e;
        else if (e < WQ_END) src = Wq + (e - XN);
        else if (e < WK_END) src = Wk + (e - WQ_END);
        else if (e < WV_END) src = Wv + (e - WK_END);
        else                 src = Wp + (e - WV_END);
        float4 v = *(const float4*)src;
        *(uint2*)(dst + e) = make_uint2(pk2(v.x, v.y), pk2(v.z, v.w));
        return;
    }
    int wave = ((bx - CVT_BLOCKS) * 256 + threadIdx.x) >> 6;
    int lane = threadIdx.x & 63;
    int step = step_p[0];
    int valid = (step >= 0 && step < NSTEPS);
    int sc = valid ? step : 0;
    const float* xr = x + wave * DIM + lane * 16;
    float xf[16];
#pragma unroll
    for (int q = 0; q < 4; q++) {
        float4 v4 = *(const float4*)(xr + q * 4);
        xf[q * 4 + 0] = v4.x; xf[q * 4 + 1] = v4.y;
        xf[q * 4 + 2] = v4.z; xf[q * 4 + 3] = v4.w;
    }
    float sums[8];
#pragma unroll
    for (int j = 0; j < 8; j++) {
        const float* ar = (j < 4 ? Aq + sc * RANK * DIM + j * DIM
                                 : Av + sc * RANK * DIM + (j - 4) * DIM) + lane * 16;
        float s = 0.f;
#pragma unroll
        for (int q = 0; q < 4; q++) {
            float4 a4 = *(const float4*)(ar + q * 4);
            s += xf[q * 4 + 0] * a4.x + xf[q * 4 + 1] * a4.y
               + xf[q * 4 + 2] * a4.z + xf[q * 4 + 3] * a4.w;
        }
#pragma unroll
        for (int o = 32; o > 0; o >>= 1) s += __shfl_xor(s, o, 64);
        sums[j] = s;
    }
    if (!valid) {
#pragma unroll
        for (int j = 0; j < 8; j++) sums[j] = 0.f;
    }
    if (lane == 0) {
        tq[wave * 4 + 0] = sums[0]; tq[wave * 4 + 1] = sums[1];
        tq[wave * 4 + 2] = sums[2]; tq[wave * 4 + 3] = sums[3];
        tv[wave * 4 + 0] = sums[4]; tv[wave * 4 + 1] = sums[5];
        tv[wave * 4 + 2] = sums[6]; tv[wave * 4 + 3] = sums[7];
    }
}

// ---------------- QKV GEMM + fused post (LoRA/RMS/RoPE/gain/vtrans) ---------
// Verified R3/R6 form: 128x128 tile, BK=64, single-buffer (best measured:
// 46 us warm; all dbuf/BK128 variants regressed — see session journal R1-R7).
// Grid 384 = 32bm x 12bn, bm-grouped per XCD. Wave owns one head -> RMS local.
__global__ __launch_bounds__(256) void k_gemm_qkv(
    const u16* __restrict__ A, const u16* __restrict__ B,
    u16* __restrict__ qkv, u16* __restrict__ vtb,
    const float* __restrict__ tq, const float* __restrict__ Bq,
    const float* __restrict__ tv, const float* __restrict__ Bv,
    const float* __restrict__ gain, const int* __restrict__ step_p)
{
    __shared__ __align__(16) u16 As[8192];
    __shared__ __align__(16) u16 Bs[8192];
    int bx = blockIdx.x;
    int xcd = bx & 7, o = bx >> 3;               // o in [0,48)
    int bm = xcd * 4 + (o & 3);                  // [0,32)
    int bn = o >> 2;                             // [0,12)
    int t = threadIdx.x, lane = t & 63, w = t >> 6;
    int wy = w >> 1, wx = w & 1;
    int wb = t & ~63;
    int quad = lane >> 4, n16 = lane & 15;
    f32x4 acc[4][4];
#pragma unroll
    for (int i = 0; i < 4; i++)
#pragma unroll
        for (int j = 0; j < 4; j++) acc[i][j] = (f32x4){0.f, 0.f, 0.f, 0.f};

    int goff[4];
#pragma unroll
    for (int u = 0; u < 4; u++) {
        int idx = u * 256 + t;
        int grp = idx >> 6;
        int q_ = (idx >> 4) & 3, m = idx & 15;
        goff[u] = ((grp >> 1) * 16 + m) * DIM + (grp & 1) * 32 + q_ * 8;
    }
    const u16* Ab = A + bm * 128 * DIM;
    const u16* Bb = B + bn * 128 * DIM;

#pragma unroll 1
    for (int kb = 0; kb < 16; kb++) {
        int k0 = kb * 64;
        __syncthreads();
#pragma unroll
        for (int u = 0; u < 4; u++)
            glds16(Ab + goff[u] + k0, As + (u * 256 + wb) * 8);
#pragma unroll
        for (int u = 0; u < 4; u++)
            glds16(Bb + goff[u] + k0, Bs + (u * 256 + wb) * 8);
        __syncthreads();
#pragma unroll
        for (int c = 0; c < 2; c++) {
            bf16x8 af[4], bfr[4];
#pragma unroll
            for (int i = 0; i < 4; i++)
                af[i] = *(const bf16x8*)(As + (((wy * 4 + i) * 2 + c) * 64 + lane) * 8);
#pragma unroll
            for (int j = 0; j < 4; j++)
                bfr[j] = *(const bf16x8*)(Bs + (((wx * 4 + j) * 2 + c) * 64 + lane) * 8);
#pragma unroll
            for (int i = 0; i < 4; i++)
#pragma unroll
                for (int j = 0; j < 4; j++)
                    acc[i][j] = __builtin_amdgcn_mfma_f32_16x16x32_bf16(af[i], bfr[j], acc[i][j], 0, 0, 0);
        }
    }

    // ---------------- fused epilogue (wave-local: wave owns one head) -------
    int step = step_p[0];
    int sc = (step >= 0 && step < NSTEPS) ? step : 0;
    int row_base = bm * 128 + wy * 64 + quad * 4;

    if (bn < 10) {
        bool isq = (bn < 8);
        int h2 = isq ? (bn * 2 + wx) : ((bn - 8) * 2 + wx);   // head idx
        int colbase = isq ? (h2 * 64) : (1024 + h2 * 64);
        // LoRA add for q (tq zeroed when step invalid)
        if (isq) {
            float4 B4[4];
#pragma unroll
            for (int j = 0; j < 4; j++)
                B4[j] = *(const float4*)(Bq + (sc * DIM + h2 * 64 + j * 16 + n16) * RANK);
#pragma unroll
            for (int i = 0; i < 4; i++)
#pragma unroll
                for (int r = 0; r < 4; r++) {
                    float4 t4 = *(const float4*)(tq + (row_base + i * 16 + r) * 4);
#pragma unroll
                    for (int j = 0; j < 4; j++)
                        acc[i][j][r] += t4.x * B4[j].x + t4.y * B4[j].y
                                      + t4.z * B4[j].z + t4.w * B4[j].w;
                }
        }
        float postmul = isq ? (gain[h2] * 0.125f * 1.4426950408889634f) : 1.f;
        float invf = exp2f(-(float)n16 * 0.8304820237218405f);  // log2(10000)/16
#pragma unroll
        for (int i = 0; i < 4; i++)
#pragma unroll
            for (int r = 0; r < 4; r++) {
                // per-row sum of squares over the head's 64 cols (wave-local)
                float s = acc[i][0][r] * acc[i][0][r] + acc[i][1][r] * acc[i][1][r]
                        + acc[i][2][r] * acc[i][2][r] + acc[i][3][r] * acc[i][3][r];
#pragma unroll
                for (int o2 = 1; o2 < 16; o2 <<= 1) s += __shfl_xor(s, o2, 64);
                float rr = rsqrtf(s * (1.f / 64.f) + 1.1920928955078125e-7f);
                int row = row_base + i * 16 + r;
                float v0 = acc[i][0][r] * rr, v1 = acc[i][1][r] * rr;
                float v2 = acc[i][2][r] * rr, v3 = acc[i][3][r] * rr;
                // RoPE: cols 0..15 pair with 16..31; 32..63 pass-through
                float ang = (float)(row & 2047) * invf;
                float cs = cosf(ang), sn = sinf(ang);
                float o0 = v0 * cs + v1 * sn;
                float o1 = -v0 * sn + v1 * cs;
                u16* dst = qkv + row * 1536 + colbase + n16;
                dst[0]  = f2bf(o0 * postmul);
                dst[16] = f2bf(o1 * postmul);
                dst[32] = f2bf(v2 * postmul);
                dst[48] = f2bf(v3 * postmul);
            }
    } else {
        // V: LoRA add then transposed write to vt[b][g][d][s]
        int g = (bn - 10) * 2 + wx;                  // [0,4)
        float4 B4[4];
#pragma unroll
        for (int j = 0; j < 4; j++)
            B4[j] = *(const float4*)(Bv + (sc * (NKV * HD) + g * 64 + j * 16 + n16) * RANK);
#pragma unroll
        for (int i = 0; i < 4; i++) {
#pragma unroll
            for (int r = 0; r < 4; r++) {
                float4 t4 = *(const float4*)(tv + (row_base + i * 16 + r) * 4);
#pragma unroll
                for (int j = 0; j < 4; j++)
                    acc[i][j][r] += t4.x * B4[j].x + t4.y * B4[j].y
                                  + t4.z * B4[j].z + t4.w * B4[j].w;
            }
            int row0 = row_base + i * 16;            // 4 consecutive rows r=0..3
            int b = row0 >> 11, s0 = row0 & 2047;
#pragma unroll
            for (int j = 0; j < 4; j++) {
                int d = j * 16 + n16;
                uint2 pkv = make_uint2(pk2(acc[i][j][0], acc[i][j][1]),
                                       pk2(acc[i][j][2], acc[i][j][3]));
                *(uint2*)(vtb + ((b * NKV + g) * HD + d) * SEQ + s0) = pkv;
            }
        }
    }
}

// ---------------- PROJ GEMM: 128x64 tile, fp32 C, XCD swizzle (R0 form) -----
__global__ __launch_bounds__(256) void k_gemm_proj(
    const u16* __restrict__ A, const u16* __restrict__ B,
    float* __restrict__ C)
{
    __shared__ __align__(16) u16 As[8192];
    __shared__ __align__(16) u16 Bs[4096];
    int bx = blockIdx.x;
    int bn = (bx & 7) * 2 + ((bx >> 3) & 1);
    int bm = bx >> 4;
    int t = threadIdx.x, lane = t & 63, w = t >> 6;
    int wy = w >> 1, wx = w & 1;
    int wb = t & ~63;
    f32x4 acc[4][2];
#pragma unroll
    for (int i = 0; i < 4; i++)
#pragma unroll
        for (int j = 0; j < 2; j++) acc[i][j] = (f32x4){0.f, 0.f, 0.f, 0.f};

    int goffA[4], goffB[2];
#pragma unroll
    for (int u = 0; u < 4; u++) {
        int idx = u * 256 + t;
        int grp = idx >> 6;
        int q_ = (idx >> 4) & 3, m = idx & 15;
        goffA[u] = ((grp >> 1) * 16 + m) * DIM + (grp & 1) * 32 + q_ * 8;
    }
#pragma unroll
    for (int u = 0; u < 2; u++) {
        int idx = u * 256 + t;
        int grp = idx >> 6;
        int q_ = (idx >> 4) & 3, m = idx & 15;
        goffB[u] = ((grp >> 1) * 16 + m) * DIM + (grp & 1) * 32 + q_ * 8;
    }
    const u16* Ab = A + bm * 128 * DIM;
    const u16* Bb = B + bn * 64 * DIM;

#pragma unroll 1
    for (int kb = 0; kb < 16; kb++) {
        int k0 = kb * 64;
        __syncthreads();
#pragma unroll
        for (int u = 0; u < 4; u++)
            glds16(Ab + goffA[u] + k0, As + (u * 256 + wb) * 8);
#pragma unroll
        for (int u = 0; u < 2; u++)
            glds16(Bb + goffB[u] + k0, Bs + (u * 256 + wb) * 8);
        __syncthreads();
#pragma unroll
        for (int c = 0; c < 2; c++) {
            bf16x8 af[4], bfr[2];
#pragma unroll
            for (int i = 0; i < 4; i++)
                af[i] = *(const bf16x8*)(As + (((wy * 4 + i) * 2 + c) * 64 + lane) * 8);
#pragma unroll
            for (int j = 0; j < 2; j++)
                bfr[j] = *(const bf16x8*)(Bs + (((wx * 2 + j) * 2 + c) * 64 + lane) * 8);
#pragma unroll
            for (int i = 0; i < 4; i++)
#pragma unroll
                for (int j = 0; j < 2; j++)
                    acc[i][j] = __builtin_amdgcn_mfma_f32_16x16x32_bf16(af[i], bfr[j], acc[i][j], 0, 0, 0);
        }
    }
    int quad = lane >> 4, n16 = lane & 15;
#pragma unroll
    for (int i = 0; i < 4; i++)
#pragma unroll
        for (int j = 0; j < 2; j++) {
            int col = bn * 64 + wx * 32 + j * 16 + n16;
#pragma unroll
            for (int r = 0; r < 4; r++) {
                int rowm = bm * 128 + wy * 64 + i * 16 + quad * 4 + r;
                C[rowm * DIM + col] = acc[i][j][r];
            }
        }
}

// ---------------- ATT: L2-direct K/V, no LDS staging, no barriers -----------
// R11: K/V per (b,g) = 512 KB, L2-resident on its XCD (blocks grouped by
// bx&7). LDS staging made 4 waves re-read each tile 4x from LDS (~90 KB
// LDS traffic/tile-block == the per-CU bottleneck; per-tile cost didn't
// scale with streams in R10). Now MFMA A-operands (K, V^T) load DIRECTLY
// from global/L2 — per-lane 16B, each 16-row fragment = 16 full 64B lines
// (no over-fetch). No kf/vf, no glds, no barriers, no vmcnt: waves fully
// independent (pb is wave-private). LDS 8 KB. Guide: Common-mistake #7
// (m169: drop staging when data L2-fits, +26% there).
__global__ __launch_bounds__(256) void k_attn(
    const u16* __restrict__ qkv, const u16* __restrict__ vt,
    const float* __restrict__ gain, u16* __restrict__ y)
{
    __shared__ __align__(16) u16 pb[4][1024];
    int bx = blockIdx.x;
    int bgid = bx & 7, inner = bx >> 3;          // inner in [0,128)
    int b = bgid >> 2, g = bgid & 3;
    int h = g * 4 + (inner & 3);
    int qt = 31 - (inner >> 2);                  // longest blocks dispatch first
    int t = threadIdx.x, lane = t & 63, w = t >> 6;
    int quad = lane >> 4, n16 = lane & 15;
    float negM = -11.67f * fabsf(gain[h]);

    // K fragment base: row=key (stride 1536), cols 1024+g*64 .. +64
    // lane reads K[key = nt*16+n16][d = ck*32 + quad*8 ..+8]
    const u16* kfr = qkv + b * SEQ * 1536 + 1024 + g * HD + n16 * 1536 + quad * 8;
    // V^T fragment base: row=d (stride 2048=SEQ), cols=s
    // lane reads Vt[d = dt*16+n16][s = kt*64 + ck*32 + quad*8 ..+8]
    const u16* vfr = vt + (b * NKV + g) * HD * SEQ + n16 * SEQ + quad * 8;
    u16* pw = pb[w];

    f32x4 acc[4];
    float ps = 0.f;
#pragma unroll
    for (int i = 0; i < 4; i++) acc[i] = (f32x4){0.f, 0.f, 0.f, 0.f};
    int qrow = qt * 64 + w * 16 + n16;
    bf16x8 qlo, qhi;
    {
        const u16* qp = qkv + (b * SEQ + qrow) * 1536 + h * HD + quad * 8;
        qlo = *(const bf16x8*)qp;
        qhi = *(const bf16x8*)(qp + 32);
    }

    int ktEnd = qt + 1;
#pragma unroll 1
    for (int kt = 0; kt < ktEnd; kt++) {
        bool diag = (kt == ktEnd - 1);
        // ---- QK^T: A = K fragments straight from L2 ----
        const u16* kb_ = kfr + kt * (64 * 1536);
        bf16x8 ka[4][2];
#pragma unroll
        for (int nt = 0; nt < 4; nt++) {
            ka[nt][0] = *(const bf16x8*)(kb_ + nt * 16 * 1536);
            ka[nt][1] = *(const bf16x8*)(kb_ + nt * 16 * 1536 + 32);
        }
        f32x4 st[4];
        __builtin_amdgcn_s_setprio(1);
#pragma unroll
        for (int nt = 0; nt < 4; nt++) {
            f32x4 sa = (f32x4){0.f, 0.f, 0.f, 0.f};
            sa = __builtin_amdgcn_mfma_f32_16x16x32_bf16(ka[nt][0], qlo, sa, 0, 0, 0);
            sa = __builtin_amdgcn_mfma_f32_16x16x32_bf16(ka[nt][1], qhi, sa, 0, 0, 0);
            st[nt] = sa;
        }
        __builtin_amdgcn_s_setprio(0);
        // ---- softmax (static max) ----
        float pr[4][4];
        if (diag) {
            int kb0 = kt * 64;
#pragma unroll
            for (int nt = 0; nt < 4; nt++)
#pragma unroll
                for (int r = 0; r < 4; r++) {
                    int key = kb0 + nt * 16 + quad * 4 + r;
                    float e = exp2f(st[nt][r] + negM);
                    e = (key > qrow) ? 0.f : e;
                    pr[nt][r] = e;
                    ps += e;
                }
        } else {
#pragma unroll
            for (int nt = 0; nt < 4; nt++)
#pragma unroll
                for (int r = 0; r < 4; r++) {
                    float e = exp2f(st[nt][r] + negM);
                    pr[nt][r] = e;
                    ps += e;
                }
        }
        // ---- pack P -> pb (wave-private LDS) ----
#pragma unroll
        for (int nt = 0; nt < 4; nt++) {
            u32 lo = pk2t(pr[nt][0], pr[nt][1]);
            u32 hi = pk2t(pr[nt][2], pr[nt][3]);
            int ck = nt >> 1;
            int qbk = (nt & 1) * 2 + (quad >> 1);
            int byteoff = (ck * 64 + qbk * 16 + n16) * 16 + (quad & 1) * 8;
            *(uint2*)((char*)pw + byteoff) = make_uint2(lo, hi);
        }
        asm volatile("s_waitcnt lgkmcnt(0)" ::: "memory");
        // ---- PV: A = V^T fragments straight from L2 ----
        const u16* vb_ = vfr + kt * 64;
        __builtin_amdgcn_s_setprio(1);
#pragma unroll
        for (int ck = 0; ck < 2; ck++) {
            bf16x8 pfr = *(bf16x8*)(pw + (ck * 64 + lane) * 8);
#pragma unroll
            for (int dt = 0; dt < 4; dt++) {
                bf16x8 va = *(const bf16x8*)(vb_ + dt * 16 * SEQ + ck * 32);
                acc[dt] = __builtin_amdgcn_mfma_f32_16x16x32_bf16(va, pfr, acc[dt], 0, 0, 0);
            }
        }
        __builtin_amdgcn_s_setprio(0);
        asm volatile("" ::: "memory");
    }
    // normalize + write y
    {
        float pt = ps + __shfl_xor(ps, 16, 64);
        pt += __shfl_xor(pt, 32, 64);
        float li = 1.f / pt;
#pragma unroll
        for (int dt = 0; dt < 4; dt++) {
            uint2 o = make_uint2(pk2(acc[dt][0] * li, acc[dt][1] * li),
                                 pk2(acc[dt][2] * li, acc[dt][3] * li));
            int d = dt * 16 + quad * 4;
            *(uint2*)(y + (b * SEQ + qrow) * DIM + h * HD + d) = o;
        }
    }
}

// ---------------------------------------------------------------------------
extern "C" void kernel_launch(void* const* d_in, const int* in_sizes, int n_in,
                              void* d_out, int out_size, void* d_ws, size_t ws_size,
                              hipStream_t stream)
{
    (void)in_sizes; (void)n_in; (void)out_size; (void)ws_size;
    const float* x     = (const float*)d_in[0];
    const float* Wq    = (const float*)d_in[1];
    const float* Wk    = (const float*)d_in[2];
    const float* Wv    = (const float*)d_in[3];
    const float* Wproj = (const float*)d_in[4];
    const float* qgain = (const float*)d_in[5];
    const float* Aq    = (const float*)d_in[6];
    const float* Bq    = (const float*)d_in[7];
    const float* Av    = (const float*)d_in[8];
    const float* Bv    = (const float*)d_in[9];
    const int*   step  = (const int*)d_in[10];

    // ws layout: cvt [xb 8MB | Wqkv 3MB | Wproj 2MB] + qkv 12MB +
    // tq/tv (128KB) + vt (2MB). y overlays xb (dead after qkv GEMM).
    char* ws = (char*)d_ws;
    u16* wsbf = (u16*)ws;
    u16* xb   = wsbf;
    u16* wf   = wsbf + XN;
    u16* wp   = wsbf + WV_END;
    u16* qkv  = (u16*)(ws + 13631488);
    float* tq = (float*)(ws + 26214400);
    float* tv = tq + 16384;
    u16* vt   = (u16*)(ws + 26607616);
    u16* y    = xb;

    k_prep<<<CVT_BLOCKS + LORA_BLOCKS, 256, 0, stream>>>(x, Wq, Wk, Wv, Wproj, wsbf,
                                                         Aq, Av, step, tq, tv);
    k_gemm_qkv<<<384, 256, 0, stream>>>(xb, wf, qkv, vt, tq, Bq, tv, Bv, qgain, step);
    k_attn<<<1024, 256, 0, stream>>>(qkv, vt, qgain, y);
    k_gemm_proj<<<512, 256, 0, stream>>>(y, wp, (float*)d_out);
}

// Round 12
// 207.050 us; speedup vs baseline: 1.4939x; 1.4939x over previous
//
#include <hip/hip_runtime.h>
#include <hip/hip_bf16.h>
#include <stdint.h>

#define DIM 1024
#define NH 16
#define NKV 4
#define HD 64
#define SEQ 2048
#define BATCH 2
#define RANK 4
#define NSTEPS 2

// bf16 conversion-region element offsets (compile-time)
#define XN      4194304            // x: 4096*1024
#define WQ_END  5242880            // + 1024*1024
#define WK_END  5505024            // + 256*1024
#define WV_END  5767168            // + 256*1024
#define CVT_BLOCKS 6656
#define LORA_BLOCKS 1024

typedef unsigned short u16;
typedef unsigned int u32;
typedef __attribute__((ext_vector_type(8))) __bf16 bf16x8;
typedef __attribute__((ext_vector_type(4))) float f32x4;

__device__ __forceinline__ float bf2f(u16 v) {
    u32 u = ((u32)v) << 16;
    return __builtin_bit_cast(float, u);
}
__device__ __forceinline__ u16 f2bf(float f) {
    u32 u = __builtin_bit_cast(u32, f);
    u32 r = (u + 0x7fffu + ((u >> 16) & 1u)) >> 16;
    return (u16)r;
}
__device__ __forceinline__ u32 pk2(float a, float b) {
    return (u32)f2bf(a) | ((u32)f2bf(b) << 16);
}
// truncation-pack two fp32->bf16 in ONE v_perm_b32 (bias cancels in softmax)
__device__ __forceinline__ u32 pk2t(float a, float b) {
    return __builtin_amdgcn_perm(__builtin_bit_cast(u32, b),
                                 __builtin_bit_cast(u32, a), 0x07060302u);
}
// async global->LDS, 16 B per lane; lptr MUST be wave-uniform (HW adds lane*16)
__device__ __forceinline__ void glds16(const u16* g, u16* l) {
    __builtin_amdgcn_global_load_lds(
        (const __attribute__((address_space(1))) u32*)g,
        (__attribute__((address_space(3))) u32*)l, 16, 0, 0);
}

// ---------------- K_PREP: fused [fp32->bf16 convert | LoRA t = x@A^T] -------
__global__ __launch_bounds__(256) void k_prep(
    const float* __restrict__ x, const float* __restrict__ Wq,
    const float* __restrict__ Wk, const float* __restrict__ Wv,
    const float* __restrict__ Wp, u16* __restrict__ dst,
    const float* __restrict__ Aq, const float* __restrict__ Av,
    const int* __restrict__ step_p, float* __restrict__ tq, float* __restrict__ tv)
{
    int bx = blockIdx.x;
    if (bx < CVT_BLOCKS) {
        int e = (bx * 256 + threadIdx.x) * 4;
        const float* src;
        if (e < XN)          src = x  + e;
        else if (e < WQ_END) src = Wq + (e - XN);
        else if (e < WK_END) src = Wk + (e - WQ_END);
        else if (e < WV_END) src = Wv + (e - WK_END);
        else                 src = Wp + (e - WV_END);
        float4 v = *(const float4*)src;
        *(uint2*)(dst + e) = make_uint2(pk2(v.x, v.y), pk2(v.z, v.w));
        return;
    }
    int wave = ((bx - CVT_BLOCKS) * 256 + threadIdx.x) >> 6;
    int lane = threadIdx.x & 63;
    int step = step_p[0];
    int valid = (step >= 0 && step < NSTEPS);
    int sc = valid ? step : 0;
    const float* xr = x + wave * DIM + lane * 16;
    float xf[16];
#pragma unroll
    for (int q = 0; q < 4; q++) {
        float4 v4 = *(const float4*)(xr + q * 4);
        xf[q * 4 + 0] = v4.x; xf[q * 4 + 1] = v4.y;
        xf[q * 4 + 2] = v4.z; xf[q * 4 + 3] = v4.w;
    }
    float sums[8];
#pragma unroll
    for (int j = 0; j < 8; j++) {
        const float* ar = (j < 4 ? Aq + sc * RANK * DIM + j * DIM
                                 : Av + sc * RANK * DIM + (j - 4) * DIM) + lane * 16;
        float s = 0.f;
#pragma unroll
        for (int q = 0; q < 4; q++) {
            float4 a4 = *(const float4*)(ar + q * 4);
            s += xf[q * 4 + 0] * a4.x + xf[q * 4 + 1] * a4.y
               + xf[q * 4 + 2] * a4.z + xf[q * 4 + 3] * a4.w;
        }
#pragma unroll
        for (int o = 32; o > 0; o >>= 1) s += __shfl_xor(s, o, 64);
        sums[j] = s;
    }
    if (!valid) {
#pragma unroll
        for (int j = 0; j < 8; j++) sums[j] = 0.f;
    }
    if (lane == 0) {
        tq[wave * 4 + 0] = sums[0]; tq[wave * 4 + 1] = sums[1];
        tq[wave * 4 + 2] = sums[2]; tq[wave * 4 + 3] = sums[3];
        tv[wave * 4 + 0] = sums[4]; tv[wave * 4 + 1] = sums[5];
        tv[wave * 4 + 2] = sums[6]; tv[wave * 4 + 3] = sums[7];
    }
}

// ---------------- QKV GEMM + fused post (LoRA/RMS/RoPE/gain/vtrans) ---------
// Verified R3/R6 form: 128x128 tile, BK=64, single-buffer (best measured:
// 46 us warm; all dbuf/BK128 variants regressed — see session journal R1-R7).
// Grid 384 = 32bm x 12bn, bm-grouped per XCD. Wave owns one head -> RMS local.
__global__ __launch_bounds__(256) void k_gemm_qkv(
    const u16* __restrict__ A, const u16* __restrict__ B,
    u16* __restrict__ qkv, u16* __restrict__ vtb,
    const float* __restrict__ tq, const float* __restrict__ Bq,
    const float* __restrict__ tv, const float* __restrict__ Bv,
    const float* __restrict__ gain, const int* __restrict__ step_p)
{
    __shared__ __align__(16) u16 As[8192];
    __shared__ __align__(16) u16 Bs[8192];
    int bx = blockIdx.x;
    int xcd = bx & 7, o = bx >> 3;               // o in [0,48)
    int bm = xcd * 4 + (o & 3);                  // [0,32)
    int bn = o >> 2;                             // [0,12)
    int t = threadIdx.x, lane = t & 63, w = t >> 6;
    int wy = w >> 1, wx = w & 1;
    int wb = t & ~63;
    int quad = lane >> 4, n16 = lane & 15;
    f32x4 acc[4][4];
#pragma unroll
    for (int i = 0; i < 4; i++)
#pragma unroll
        for (int j = 0; j < 4; j++) acc[i][j] = (f32x4){0.f, 0.f, 0.f, 0.f};

    int goff[4];
#pragma unroll
    for (int u = 0; u < 4; u++) {
        int idx = u * 256 + t;
        int grp = idx >> 6;
        int q_ = (idx >> 4) & 3, m = idx & 15;
        goff[u] = ((grp >> 1) * 16 + m) * DIM + (grp & 1) * 32 + q_ * 8;
    }
    const u16* Ab = A + bm * 128 * DIM;
    const u16* Bb = B + bn * 128 * DIM;

#pragma unroll 1
    for (int kb = 0; kb < 16; kb++) {
        int k0 = kb * 64;
        __syncthreads();
#pragma unroll
        for (int u = 0; u < 4; u++)
            glds16(Ab + goff[u] + k0, As + (u * 256 + wb) * 8);
#pragma unroll
        for (int u = 0; u < 4; u++)
            glds16(Bb + goff[u] + k0, Bs + (u * 256 + wb) * 8);
        __syncthreads();
#pragma unroll
        for (int c = 0; c < 2; c++) {
            bf16x8 af[4], bfr[4];
#pragma unroll
            for (int i = 0; i < 4; i++)
                af[i] = *(const bf16x8*)(As + (((wy * 4 + i) * 2 + c) * 64 + lane) * 8);
#pragma unroll
            for (int j = 0; j < 4; j++)
                bfr[j] = *(const bf16x8*)(Bs + (((wx * 4 + j) * 2 + c) * 64 + lane) * 8);
#pragma unroll
            for (int i = 0; i < 4; i++)
#pragma unroll
                for (int j = 0; j < 4; j++)
                    acc[i][j] = __builtin_amdgcn_mfma_f32_16x16x32_bf16(af[i], bfr[j], acc[i][j], 0, 0, 0);
        }
    }

    // ---------------- fused epilogue (wave-local: wave owns one head) -------
    int step = step_p[0];
    int sc = (step >= 0 && step < NSTEPS) ? step : 0;
    int row_base = bm * 128 + wy * 64 + quad * 4;

    if (bn < 10) {
        bool isq = (bn < 8);
        int h2 = isq ? (bn * 2 + wx) : ((bn - 8) * 2 + wx);   // head idx
        int colbase = isq ? (h2 * 64) : (1024 + h2 * 64);
        // LoRA add for q (tq zeroed when step invalid)
        if (isq) {
            float4 B4[4];
#pragma unroll
            for (int j = 0; j < 4; j++)
                B4[j] = *(const float4*)(Bq + (sc * DIM + h2 * 64 + j * 16 + n16) * RANK);
#pragma unroll
            for (int i = 0; i < 4; i++)
#pragma unroll
                for (int r = 0; r < 4; r++) {
                    float4 t4 = *(const float4*)(tq + (row_base + i * 16 + r) * 4);
#pragma unroll
                    for (int j = 0; j < 4; j++)
                        acc[i][j][r] += t4.x * B4[j].x + t4.y * B4[j].y
                                      + t4.z * B4[j].z + t4.w * B4[j].w;
                }
        }
        float postmul = isq ? (gain[h2] * 0.125f * 1.4426950408889634f) : 1.f;
        float invf = exp2f(-(float)n16 * 0.8304820237218405f);  // log2(10000)/16
#pragma unroll
        for (int i = 0; i < 4; i++)
#pragma unroll
            for (int r = 0; r < 4; r++) {
                // per-row sum of squares over the head's 64 cols (wave-local)
                float s = acc[i][0][r] * acc[i][0][r] + acc[i][1][r] * acc[i][1][r]
                        + acc[i][2][r] * acc[i][2][r] + acc[i][3][r] * acc[i][3][r];
#pragma unroll
                for (int o2 = 1; o2 < 16; o2 <<= 1) s += __shfl_xor(s, o2, 64);
                float rr = rsqrtf(s * (1.f / 64.f) + 1.1920928955078125e-7f);
                int row = row_base + i * 16 + r;
                float v0 = acc[i][0][r] * rr, v1 = acc[i][1][r] * rr;
                float v2 = acc[i][2][r] * rr, v3 = acc[i][3][r] * rr;
                // RoPE: cols 0..15 pair with 16..31; 32..63 pass-through
                float ang = (float)(row & 2047) * invf;
                float cs = cosf(ang), sn = sinf(ang);
                float o0 = v0 * cs + v1 * sn;
                float o1 = -v0 * sn + v1 * cs;
                u16* dst = qkv + row * 1536 + colbase + n16;
                dst[0]  = f2bf(o0 * postmul);
                dst[16] = f2bf(o1 * postmul);
                dst[32] = f2bf(v2 * postmul);
                dst[48] = f2bf(v3 * postmul);
            }
    } else {
        // V: LoRA add then transposed write to vt[b][g][d][s]
        int g = (bn - 10) * 2 + wx;                  // [0,4)
        float4 B4[4];
#pragma unroll
        for (int j = 0; j < 4; j++)
            B4[j] = *(const float4*)(Bv + (sc * (NKV * HD) + g * 64 + j * 16 + n16) * RANK);
#pragma unroll
        for (int i = 0; i < 4; i++) {
#pragma unroll
            for (int r = 0; r < 4; r++) {
                float4 t4 = *(const float4*)(tv + (row_base + i * 16 + r) * 4);
#pragma unroll
                for (int j = 0; j < 4; j++)
                    acc[i][j][r] += t4.x * B4[j].x + t4.y * B4[j].y
                                  + t4.z * B4[j].z + t4.w * B4[j].w;
            }
            int row0 = row_base + i * 16;            // 4 consecutive rows r=0..3
            int b = row0 >> 11, s0 = row0 & 2047;
#pragma unroll
            for (int j = 0; j < 4; j++) {
                int d = j * 16 + n16;
                uint2 pkv = make_uint2(pk2(acc[i][j][0], acc[i][j][1]),
                                       pk2(acc[i][j][2], acc[i][j][3]));
                *(uint2*)(vtb + ((b * NKV + g) * HD + d) * SEQ + s0) = pkv;
            }
        }
    }
}

// ---------------- PROJ GEMM: 128x64 tile, fp32 C, XCD swizzle (R0 form) -----
__global__ __launch_bounds__(256) void k_gemm_proj(
    const u16* __restrict__ A, const u16* __restrict__ B,
    float* __restrict__ C)
{
    __shared__ __align__(16) u16 As[8192];
    __shared__ __align__(16) u16 Bs[4096];
    int bx = blockIdx.x;
    int bn = (bx & 7) * 2 + ((bx >> 3) & 1);
    int bm = bx >> 4;
    int t = threadIdx.x, lane = t & 63, w = t >> 6;
    int wy = w >> 1, wx = w & 1;
    int wb = t & ~63;
    f32x4 acc[4][2];
#pragma unroll
    for (int i = 0; i < 4; i++)
#pragma unroll
        for (int j = 0; j < 2; j++) acc[i][j] = (f32x4){0.f, 0.f, 0.f, 0.f};

    int goffA[4], goffB[2];
#pragma unroll
    for (int u = 0; u < 4; u++) {
        int idx = u * 256 + t;
        int grp = idx >> 6;
        int q_ = (idx >> 4) & 3, m = idx & 15;
        goffA[u] = ((grp >> 1) * 16 + m) * DIM + (grp & 1) * 32 + q_ * 8;
    }
#pragma unroll
    for (int u = 0; u < 2; u++) {
        int idx = u * 256 + t;
        int grp = idx >> 6;
        int q_ = (idx >> 4) & 3, m = idx & 15;
        goffB[u] = ((grp >> 1) * 16 + m) * DIM + (grp & 1) * 32 + q_ * 8;
    }
    const u16* Ab = A + bm * 128 * DIM;
    const u16* Bb = B + bn * 64 * DIM;

#pragma unroll 1
    for (int kb = 0; kb < 16; kb++) {
        int k0 = kb * 64;
        __syncthreads();
#pragma unroll
        for (int u = 0; u < 4; u++)
            glds16(Ab + goffA[u] + k0, As + (u * 256 + wb) * 8);
#pragma unroll
        for (int u = 0; u < 2; u++)
            glds16(Bb + goffB[u] + k0, Bs + (u * 256 + wb) * 8);
        __syncthreads();
#pragma unroll
        for (int c = 0; c < 2; c++) {
            bf16x8 af[4], bfr[2];
#pragma unroll
            for (int i = 0; i < 4; i++)
                af[i] = *(const bf16x8*)(As + (((wy * 4 + i) * 2 + c) * 64 + lane) * 8);
#pragma unroll
            for (int j = 0; j < 2; j++)
                bfr[j] = *(const bf16x8*)(Bs + (((wx * 2 + j) * 2 + c) * 64 + lane) * 8);
#pragma unroll
            for (int i = 0; i < 4; i++)
#pragma unroll
                for (int j = 0; j < 2; j++)
                    acc[i][j] = __builtin_amdgcn_mfma_f32_16x16x32_bf16(af[i], bfr[j], acc[i][j], 0, 0, 0);
        }
    }
    int quad = lane >> 4, n16 = lane & 15;
#pragma unroll
    for (int i = 0; i < 4; i++)
#pragma unroll
        for (int j = 0; j < 2; j++) {
            int col = bn * 64 + wx * 32 + j * 16 + n16;
#pragma unroll
            for (int r = 0; r < 4; r++) {
                int rowm = bm * 128 + wy * 64 + i * 16 + quad * 4 + r;
                C[rowm * DIM + col] = acc[i][j][r];
            }
        }
}

// ---------------- ATT: one q-tile per block, longest-first, no split-K ------
// R10 (best measured attn: 47.6 us): grid 1024 = 4 blocks/CU. LDS-staged K/V
// (R11's L2-direct variant was 3.2x WORSE: per-lane fragment loads are
// uncoalesced, latency-bound). K/V 2-buffer + counted vmcnt(4); longest-first
// dispatch (qt = 31 - idx) balances causal tile counts; XCD grouping on
// (b,g) keeps K/V L2-resident; setprio around MFMA clusters (T5).
__global__ __launch_bounds__(256) void k_attn(
    const u16* __restrict__ qkv, const u16* __restrict__ vt,
    const float* __restrict__ gain, u16* __restrict__ y)
{
    __shared__ __align__(16) u16 kf[2][4096];
    __shared__ __align__(16) u16 vf[2][4096];
    __shared__ __align__(16) u16 pb[4][1024];
    int bx = blockIdx.x;
    int bgid = bx & 7, inner = bx >> 3;          // inner in [0,128)
    int b = bgid >> 2, g = bgid & 3;
    int h = g * 4 + (inner & 3);
    int qt = 31 - (inner >> 2);                  // longest blocks dispatch first
    int t = threadIdx.x, lane = t & 63, w = t >> 6, wb = t & ~63;
    int quad = lane >> 4, n16 = lane & 15;
    float negM = -11.67f * fabsf(gain[h]);

    const u16* kbase = qkv + b * SEQ * 1536 + 1024 + g * HD;
    const u16* vbase = vt + (b * NKV + g) * HD * SEQ;

    int koff0, koff1, voff0, voff1;
    {
        int s0 = t, r0 = s0 >> 3, c0 = (s0 & 7) ^ (r0 & 7);
        koff0 = r0 * 1536 + c0 * 8;  voff0 = r0 * 2048 + c0 * 8;
        int s1 = 256 + t, r1 = s1 >> 3, c1 = (s1 & 7) ^ (r1 & 7);
        koff1 = r1 * 1536 + c1 * 8;  voff1 = r1 * 2048 + c1 * 8;
    }
    int swb = n16 & 7;
    int o0 = n16 * 8 + (quad ^ swb);
    int o1 = n16 * 8 + ((4 + quad) ^ swb);
    u16* pw = pb[w];

    f32x4 acc[4];
    float ps = 0.f;
#pragma unroll
    for (int i = 0; i < 4; i++) acc[i] = (f32x4){0.f, 0.f, 0.f, 0.f};
    int qrow = qt * 64 + w * 16 + n16;
    bf16x8 qlo, qhi;
    {
        const u16* qp = qkv + (b * SEQ + qrow) * 1536 + h * HD + quad * 8;
        qlo = *(const bf16x8*)qp;
        qhi = *(const bf16x8*)(qp + 32);
    }

    auto stage = [&](int kt, int p) {
        const u16* kp = kbase + kt * (64 * 1536);
        const u16* vp = vbase + kt * 64;
        glds16(kp + koff0, kf[p] + wb * 8);
        glds16(kp + koff1, kf[p] + (256 + wb) * 8);
        glds16(vp + voff0, vf[p] + wb * 8);
        glds16(vp + voff1, vf[p] + (256 + wb) * 8);
    };
    auto tilecomp = [&](int kt, int p, bool diag) {
        f32x4 st[4];
        __builtin_amdgcn_s_setprio(1);
#pragma unroll
        for (int nt = 0; nt < 4; nt++) {
            f32x4 sa = (f32x4){0.f, 0.f, 0.f, 0.f};
            sa = __builtin_amdgcn_mfma_f32_16x16x32_bf16(*(bf16x8*)(kf[p] + (nt * 128 + o0) * 8), qlo, sa, 0, 0, 0);
            sa = __builtin_amdgcn_mfma_f32_16x16x32_bf16(*(bf16x8*)(kf[p] + (nt * 128 + o1) * 8), qhi, sa, 0, 0, 0);
            st[nt] = sa;
        }
        __builtin_amdgcn_s_setprio(0);
        float pr[4][4];
        if (diag) {
            int kb0 = kt * 64;
#pragma unroll
            for (int nt = 0; nt < 4; nt++)
#pragma unroll
                for (int r = 0; r < 4; r++) {
                    int key = kb0 + nt * 16 + quad * 4 + r;
                    float e = exp2f(st[nt][r] + negM);
                    e = (key > qrow) ? 0.f : e;
                    pr[nt][r] = e;
                    ps += e;
                }
        } else {
#pragma unroll
            for (int nt = 0; nt < 4; nt++)
#pragma unroll
                for (int r = 0; r < 4; r++) {
                    float e = exp2f(st[nt][r] + negM);
                    pr[nt][r] = e;
                    ps += e;
                }
        }
#pragma unroll
        for (int nt = 0; nt < 4; nt++) {
            u32 lo = pk2t(pr[nt][0], pr[nt][1]);
            u32 hi = pk2t(pr[nt][2], pr[nt][3]);
            int ck = nt >> 1;
            int qbk = (nt & 1) * 2 + (quad >> 1);
            int byteoff = (ck * 64 + qbk * 16 + n16) * 16 + (quad & 1) * 8;
            *(uint2*)((char*)pw + byteoff) = make_uint2(lo, hi);
        }
        asm volatile("s_waitcnt lgkmcnt(0)" ::: "memory");
        __builtin_amdgcn_s_setprio(1);
#pragma unroll
        for (int ck = 0; ck < 2; ck++) {
            bf16x8 pfr = *(bf16x8*)(pw + (ck * 64 + lane) * 8);
            int oo = ck ? o1 : o0;
#pragma unroll
            for (int dt = 0; dt < 4; dt++)
                acc[dt] = __builtin_amdgcn_mfma_f32_16x16x32_bf16(*(bf16x8*)(vf[p] + (dt * 128 + oo) * 8), pfr, acc[dt], 0, 0, 0);
        }
        __builtin_amdgcn_s_setprio(0);
        asm volatile("" ::: "memory");
    };

    // single q-tile: kt 0..qt, 2-buffer pipeline (R6-verified form)
    int ktEnd = qt + 1;
    int p = 0;
    stage(0, 0);
#pragma unroll 1
    for (int kt = 0; kt < ktEnd; kt++) {
        if (kt + 1 < ktEnd) {
            stage(kt + 1, p ^ 1);
            asm volatile("s_waitcnt vmcnt(4)" ::: "memory");
        } else {
            asm volatile("s_waitcnt vmcnt(0)" ::: "memory");
        }
        __builtin_amdgcn_s_barrier();
        tilecomp(kt, p, kt == ktEnd - 1);
        asm volatile("s_waitcnt lgkmcnt(0)" ::: "memory");
        __builtin_amdgcn_s_barrier();
        p ^= 1;
    }
    // normalize + write y
    {
        float pt = ps + __shfl_xor(ps, 16, 64);
        pt += __shfl_xor(pt, 32, 64);
        float li = 1.f / pt;
#pragma unroll
        for (int dt = 0; dt < 4; dt++) {
            uint2 o = make_uint2(pk2(acc[dt][0] * li, acc[dt][1] * li),
                                 pk2(acc[dt][2] * li, acc[dt][3] * li));
            int d = dt * 16 + quad * 4;
            *(uint2*)(y + (b * SEQ + qrow) * DIM + h * HD + d) = o;
        }
    }
}

// ---------------------------------------------------------------------------
extern "C" void kernel_launch(void* const* d_in, const int* in_sizes, int n_in,
                              void* d_out, int out_size, void* d_ws, size_t ws_size,
                              hipStream_t stream)
{
    (void)in_sizes; (void)n_in; (void)out_size; (void)ws_size;
    const float* x     = (const float*)d_in[0];
    const float* Wq    = (const float*)d_in[1];
    const float* Wk    = (const float*)d_in[2];
    const float* Wv    = (const float*)d_in[3];
    const float* Wproj = (const float*)d_in[4];
    const float* qgain = (const float*)d_in[5];
    const float* Aq    = (const float*)d_in[6];
    const float* Bq    = (const float*)d_in[7];
    const float* Av    = (const float*)d_in[8];
    const float* Bv    = (const float*)d_in[9];
    const int*   step  = (const int*)d_in[10];

    // ws layout: cvt [xb 8MB | Wqkv 3MB | Wproj 2MB] + qkv 12MB +
    // tq/tv (128KB) + vt (2MB). y overlays xb (dead after qkv GEMM).
    char* ws = (char*)d_ws;
    u16* wsbf = (u16*)ws;
    u16* xb   = wsbf;
    u16* wf   = wsbf + XN;
    u16* wp   = wsbf + WV_END;
    u16* qkv  = (u16*)(ws + 13631488);
    float* tq = (float*)(ws + 26214400);
    float* tv = tq + 16384;
    u16* vt   = (u16*)(ws + 26607616);
    u16* y    = xb;

    k_prep<<<CVT_BLOCKS + LORA_BLOCKS, 256, 0, stream>>>(x, Wq, Wk, Wv, Wproj, wsbf,
                                                         Aq, Av, step, tq, tv);
    k_gemm_qkv<<<384, 256, 0, stream>>>(xb, wf, qkv, vt, tq, Bq, tv, Bv, qgain, step);
    k_attn<<<1024, 256, 0, stream>>>(qkv, vt, qgain, y);
    k_gemm_proj<<<512, 256, 0, stream>>>(y, wp, (float*)d_out);
}